// Round 7
// baseline (431.635 us; speedup 1.0000x reference)
//
#include <hip/hip_runtime.h>
#include <hip/hip_fp16.h>
#include <math.h>

#define BATCH 8
#define SCAN_T 256
#define SCAN_E 8
#define SCAN_TILE (SCAN_T * SCAN_E)   // 2048 elems per scan block

union H2U { __half2 h; unsigned u; };

// ---------------- count + repack fused ----------------
// Blocks [0, cntBlocks): PURE atomic histogram (critical path, launched first).
//   cnt[v] += 2 per corner; rank[corner] = pre-add value (even), coalesced store.
// Remaining blocks: repack vert [B][N][3] fp32 -> vh [N][B] half4 (uint2, 8B).
// The repack streaming rides the memory pipe that the atomic-latency-bound
// count waves leave idle (count alone: 10% HBM, 0.3% VALU).
__global__ void count_repack_kernel(const int* __restrict__ faces,
                                    int* __restrict__ cnt,
                                    int* __restrict__ rank,
                                    const float* __restrict__ vert,
                                    uint2* __restrict__ vh,
                                    int N, int F, int cntBlocks) {
    if ((int)blockIdx.x < cntBlocks) {
        int f = blockIdx.x * blockDim.x + threadIdx.x;
        if (f >= F) return;
        int i = faces[3 * f + 0];
        int j = faces[3 * f + 1];
        int k = faces[3 * f + 2];
        rank[3 * f + 0] = atomicAdd(&cnt[i], 2);
        rank[3 * f + 1] = atomicAdd(&cnt[j], 2);
        rank[3 * f + 2] = atomicAdd(&cnt[k], 2);
    } else {
        int u = (blockIdx.x - cntBlocks) * blockDim.x + threadIdx.x;
        if (u >= N * BATCH) return;
        int v = u >> 3;
        int b = u & 7;
        size_t src = ((size_t)b * N + v) * 3;
        H2U xy, zw;
        xy.h = __floats2half2_rn(vert[src], vert[src + 1]);
        zw.h = __floats2half2_rn(vert[src + 2], 0.0f);
        uint2 w; w.x = xy.u; w.y = zw.u;
        vh[u] = w;   // u == v*8 + b
    }
}

// ---------------- single-pass decoupled-lookback scan ----------------
// Dynamic ticket => processing order == ticket order, so every predecessor
// ticket is held by a resident block (no dispatch-order assumption, G16-safe).
// state[t] = (flag<<32) | value; flag 1 = aggregate ready, 2 = prefix ready.
__global__ void scan_lookback_kernel(const int* __restrict__ cnt, int* __restrict__ off,
                                     unsigned long long* __restrict__ state,
                                     unsigned* __restrict__ ticket, int N) {
    __shared__ int sh[SCAN_T];
    __shared__ int sh_tkt;
    __shared__ int sh_prefix;
    if (threadIdx.x == 0) sh_tkt = (int)atomicAdd(ticket, 1u);
    __syncthreads();
    int tkt = sh_tkt;

    int base = tkt * SCAN_TILE + threadIdx.x * SCAN_E;
    int vals[SCAN_E];
    int s = 0;
    #pragma unroll
    for (int e = 0; e < SCAN_E; ++e) {
        int v = (base + e < N) ? cnt[base + e] : 0;
        vals[e] = v; s += v;
    }
    sh[threadIdx.x] = s;
    __syncthreads();
    for (int d = 1; d < SCAN_T; d <<= 1) {
        int t = (threadIdx.x >= (unsigned)d) ? sh[threadIdx.x - d] : 0;
        __syncthreads();
        sh[threadIdx.x] += t;
        __syncthreads();
    }
    int total = sh[SCAN_T - 1];

    if (threadIdx.x == 0) {
        int prefix = 0;
        if (tkt == 0) {
            __hip_atomic_store(&state[0], (2ULL << 32) | (unsigned)total,
                               __ATOMIC_RELEASE, __HIP_MEMORY_SCOPE_AGENT);
        } else {
            __hip_atomic_store(&state[tkt], (1ULL << 32) | (unsigned)total,
                               __ATOMIC_RELEASE, __HIP_MEMORY_SCOPE_AGENT);
            int p = tkt - 1;
            while (true) {
                unsigned long long w = __hip_atomic_load(&state[p], __ATOMIC_ACQUIRE,
                                                         __HIP_MEMORY_SCOPE_AGENT);
                unsigned flag = (unsigned)(w >> 32);
                if (flag == 0) { __builtin_amdgcn_s_sleep(1); continue; }
                prefix += (int)(unsigned)w;
                if (flag == 2u) break;
                --p;
            }
            __hip_atomic_store(&state[tkt], (2ULL << 32) | (unsigned)(prefix + total),
                               __ATOMIC_RELEASE, __HIP_MEMORY_SCOPE_AGENT);
        }
        sh_prefix = prefix;
    }
    __syncthreads();

    int excl = sh_prefix + ((threadIdx.x > 0) ? sh[threadIdx.x - 1] : 0);
    #pragma unroll
    for (int e = 0; e < SCAN_E; ++e) {
        if (base + e < N) off[base + e] = excl;
        excl += vals[e];
    }
}

// ---------------- pure fill (atomic-free; R4-proven) ----------------
__global__ void fill_kernel(const int* __restrict__ faces, const int* __restrict__ off,
                            const int* __restrict__ rank, int* __restrict__ col, int F) {
    int f = blockIdx.x * blockDim.x + threadIdx.x;
    if (f >= F) return;
    int i = faces[3 * f + 0];
    int j = faces[3 * f + 1];
    int k = faces[3 * f + 2];
    int ri = rank[3 * f + 0];
    int rj = rank[3 * f + 1];
    int rk = rank[3 * f + 2];
    int2* c2 = (int2*)col;
    c2[(off[i] + ri) >> 1] = make_int2(j, k);
    c2[(off[j] + rj) >> 1] = make_int2(i, k);
    c2[(off[k] + rk) >> 1] = make_int2(i, j);
}

__device__ __forceinline__ void unpack_acc(uint2 r, float& ax, float& ay, float& az) {
    H2U xy, zw; xy.u = r.x; zw.u = r.y;
    float2 f0 = __half22float2(xy.h);
    float2 f1 = __half22float2(zw.h);
    ax += f0.x; ay += f0.y; az += f1.x;
}

// ---------------- gather + finalize: thread per (v,b), b in low 3 bits ----------------
// Lanes b=0..7 of one v read vh[s*8 + 0..7] = one fully-consumed 64B line per
// neighbor. col reads: packed CSR int2, broadcast across the 8 b-lanes.
// Unroll depth 4 int2 = 8 outstanding vh loads (avg row = 12 neighbors).
__global__ void gather_kernel(const uint2* __restrict__ vh,
                              const int* __restrict__ cnt,
                              const int* __restrict__ off,
                              const int* __restrict__ col,
                              float* __restrict__ out, int N) {
    int t = blockIdx.x * blockDim.x + threadIdx.x;
    if (t >= N * BATCH) return;
    int v = t >> 3;
    int b = t & 7;

    int c = cnt[v];
    int start = off[v];              // even
    const int2* c2 = (const int2*)col;
    int e0 = start >> 1;
    int e1 = (start + c) >> 1;

    float ax = 0.f, ay = 0.f, az = 0.f;
    int e = e0;
    for (; e + 4 <= e1; e += 4) {    // 8 independent vh gathers in flight
        int2 s01 = c2[e];
        int2 s23 = c2[e + 1];
        int2 s45 = c2[e + 2];
        int2 s67 = c2[e + 3];
        uint2 r0 = vh[((size_t)s01.x << 3) + b];
        uint2 r1 = vh[((size_t)s01.y << 3) + b];
        uint2 r2 = vh[((size_t)s23.x << 3) + b];
        uint2 r3 = vh[((size_t)s23.y << 3) + b];
        uint2 r4 = vh[((size_t)s45.x << 3) + b];
        uint2 r5 = vh[((size_t)s45.y << 3) + b];
        uint2 r6 = vh[((size_t)s67.x << 3) + b];
        uint2 r7 = vh[((size_t)s67.y << 3) + b];
        unpack_acc(r0, ax, ay, az); unpack_acc(r1, ax, ay, az);
        unpack_acc(r2, ax, ay, az); unpack_acc(r3, ax, ay, az);
        unpack_acc(r4, ax, ay, az); unpack_acc(r5, ax, ay, az);
        unpack_acc(r6, ax, ay, az); unpack_acc(r7, ax, ay, az);
    }
    for (; e < e1; ++e) {
        int2 ss = c2[e];
        uint2 r0 = vh[((size_t)ss.x << 3) + b];
        uint2 r1 = vh[((size_t)ss.y << 3) + b];
        unpack_acc(r0, ax, ay, az);
        unpack_acc(r1, ax, ay, az);
    }

    float invd = 1.0f / fmaxf((float)c, 1.0f);
    float sx = 0.f, sy = 0.f, sz = 0.f;
    unpack_acc(vh[t], sx, sy, sz);   // self (t == v*8 + b)
    float l0 = ax * invd - sx;
    float l1 = ay * invd - sy;
    float l2 = az * invd - sz;
    out[(size_t)b * N + v] = sqrtf(l0 * l0 + l1 * l1 + l2 * l2);
}

// ---------------- fp32 fallback pieces (tiny ws) ----------------

__global__ void count_only_kernel(const int* __restrict__ faces, int* __restrict__ cnt,
                                  int* __restrict__ rank, int F) {
    int f = blockIdx.x * blockDim.x + threadIdx.x;
    if (f >= F) return;
    rank[3 * f + 0] = atomicAdd(&cnt[faces[3 * f + 0]], 2);
    rank[3 * f + 1] = atomicAdd(&cnt[faces[3 * f + 1]], 2);
    rank[3 * f + 2] = atomicAdd(&cnt[faces[3 * f + 2]], 2);
}

__global__ void gather_scalar_kernel(const float* __restrict__ vert,
                                     const int* __restrict__ cnt,
                                     const int* __restrict__ off,
                                     const int* __restrict__ col,
                                     float* __restrict__ out, int N) {
    int v = blockIdx.x * blockDim.x + threadIdx.x;
    if (v >= N) return;
    int c = cnt[v];
    int start = off[v];
    int end = start + c;
    float ax[BATCH], ay[BATCH], az[BATCH];
    #pragma unroll
    for (int b = 0; b < BATCH; ++b) { ax[b] = 0.f; ay[b] = 0.f; az[b] = 0.f; }
    for (int e = start; e < end; ++e) {
        int s = col[e];
        #pragma unroll
        for (int b = 0; b < BATCH; ++b) {
            size_t base = ((size_t)b * N + s) * 3;
            ax[b] += vert[base + 0];
            ay[b] += vert[base + 1];
            az[b] += vert[base + 2];
        }
    }
    float invd = 1.0f / fmaxf((float)c, 1.0f);
    #pragma unroll
    for (int b = 0; b < BATCH; ++b) {
        size_t base = ((size_t)b * N + v) * 3;
        float l0 = ax[b] * invd - vert[base + 0];
        float l1 = ay[b] * invd - vert[base + 1];
        float l2 = az[b] * invd - vert[base + 2];
        out[(size_t)b * N + v] = sqrtf(l0 * l0 + l1 * l1 + l2 * l2);
    }
}

// ---------------- launch ----------------

static inline size_t align256(size_t x) { return (x + 255) & ~(size_t)255; }

extern "C" void kernel_launch(void* const* d_in, const int* in_sizes, int n_in,
                              void* d_out, int out_size, void* d_ws, size_t ws_size,
                              hipStream_t stream) {
    const float* vert  = (const float*)d_in[0];
    const int*   faces = (const int*)d_in[1];
    float*       out   = (float*)d_out;

    int N = out_size / BATCH;      // 500000
    int F = in_sizes[1] / 3;       // 1000000
    int E = 6 * F;

    char* ws = (char*)d_ws;
    int threads = 256;
    int nb = (N + SCAN_TILE - 1) / SCAN_TILE;   // 245 for N=500000

    // Layout: cnt[N] | ticket(256B) | state[nb] u64 | off[N] | col[E] |
    //         vh[N*B] uint2 | rank[3F]
    size_t o_cnt    = 0;
    size_t o_ticket = align256((size_t)N * 4);
    size_t o_state  = o_ticket + 256;
    size_t o_off    = o_state + align256((size_t)nb * 8);
    size_t o_col    = o_off + align256((size_t)N * 4);
    size_t o_vh     = o_col + align256((size_t)E * 4);
    size_t o_rank   = o_vh + align256((size_t)N * BATCH * sizeof(uint2));
    size_t need     = o_rank + (size_t)3 * F * 4;

    int* cnt    = (int*)(ws + o_cnt);
    unsigned* ticket = (unsigned*)(ws + o_ticket);
    unsigned long long* state = (unsigned long long*)(ws + o_state);
    int* off    = (int*)(ws + o_off);
    int* col    = (int*)(ws + o_col);

    // One memset covers cnt + ticket + state.
    hipMemsetAsync(ws, 0, o_off, stream);

    if (ws_size >= need) {
        uint2* vh  = (uint2*)(ws + o_vh);
        int*  rank = (int*)(ws + o_rank);

        int cntBlocks    = (F + threads - 1) / threads;
        int repackBlocks = (N * BATCH + threads - 1) / threads;
        count_repack_kernel<<<cntBlocks + repackBlocks, threads, 0, stream>>>(
            faces, cnt, rank, vert, vh, N, F, cntBlocks);

        scan_lookback_kernel<<<nb, SCAN_T, 0, stream>>>(cnt, off, state, ticket, N);

        fill_kernel<<<cntBlocks, threads, 0, stream>>>(faces, off, rank, col, F);

        int total = N * BATCH;
        gather_kernel<<<(total + threads - 1) / threads, threads, 0, stream>>>(
            vh, cnt, off, col, out, N);
        return;
    }

    // ---- compact fp32 fallback: rank aliases the vh region ----
    int* rank = (int*)(ws + o_vh);
    int cntBlocks = (F + threads - 1) / threads;

    count_only_kernel<<<cntBlocks, threads, 0, stream>>>(faces, cnt, rank, F);
    scan_lookback_kernel<<<nb, SCAN_T, 0, stream>>>(cnt, off, state, ticket, N);
    fill_kernel<<<cntBlocks, threads, 0, stream>>>(faces, off, rank, col, F);
    gather_scalar_kernel<<<(N + threads - 1) / threads, threads, 0, stream>>>(
        vert, cnt, off, col, out, N);
}